// Round 1
// baseline (35.122 us; speedup 1.0000x reference)
//
#include <hip/hip_runtime.h>

#define TLEN 1461

__device__ __forceinline__ float fast_tanh(float x) {
    // tanh(x) = 1 - 2/(exp(2x)+1); saturates to +-1 without NaN
    float e = __expf(2.0f * x);
    return fmaf(-2.0f, __builtin_amdgcn_rcpf(e + 1.0f), 1.0f);
}

__device__ __forceinline__ float step_fn(float x) {
    // (tanh(5x)+1)*0.5 == sigmoid(10x) = 1/(1+exp(-10x))
    float e = __expf(-10.0f * x);
    return __builtin_amdgcn_rcpf(1.0f + e);
}

// one 16->16 tanh layer; w row-major [16][16], broadcast LDS reads
__device__ __forceinline__ void layer16(const float* __restrict__ w,
                                        const float* __restrict__ b,
                                        const float h[16], float out[16]) {
    float acc[16];
#pragma unroll
    for (int j = 0; j < 16; ++j) acc[j] = b[j];
#pragma unroll
    for (int k = 0; k < 16; ++k) {
        float hk = h[k];
#pragma unroll
        for (int j4 = 0; j4 < 4; ++j4) {
            float4 w4 = *reinterpret_cast<const float4*>(&w[k * 16 + j4 * 4]);
            acc[j4 * 4 + 0] = fmaf(hk, w4.x, acc[j4 * 4 + 0]);
            acc[j4 * 4 + 1] = fmaf(hk, w4.y, acc[j4 * 4 + 1]);
            acc[j4 * 4 + 2] = fmaf(hk, w4.z, acc[j4 * 4 + 2]);
            acc[j4 * 4 + 3] = fmaf(hk, w4.w, acc[j4 * 4 + 3]);
        }
    }
#pragma unroll
    for (int j = 0; j < 16; ++j) out[j] = fast_tanh(acc[j]);
}

__global__ __launch_bounds__(256) void hydro_kernel(
    const float* __restrict__ g_t,
    const float* __restrict__ g_S,
    const float* __restrict__ g_precp,
    const float* __restrict__ g_temp,
    const float* __restrict__ g_lday,
    const float* __restrict__ g_ew1, const float* __restrict__ g_eb1,
    const float* __restrict__ g_ew2, const float* __restrict__ g_eb2,
    const float* __restrict__ g_ew3, const float* __restrict__ g_eb3,
    const float* __restrict__ g_qw1, const float* __restrict__ g_qb1,
    const float* __restrict__ g_qw2, const float* __restrict__ g_qb2,
    const float* __restrict__ g_qw3, const float* __restrict__ g_qb3,
    const float* __restrict__ g_Df, const float* __restrict__ g_Tmax,
    const float* __restrict__ g_Tmin,
    float* __restrict__ g_out, int B)
{
    __shared__ __align__(16) float s_precp[TLEN];
    __shared__ __align__(16) float s_temp[TLEN];
    __shared__ __align__(16) float s_lday[TLEN];
    __shared__ __align__(16) float s_ew1[48];
    __shared__ __align__(16) float s_eb1[16];
    __shared__ __align__(16) float s_ew2[256];
    __shared__ __align__(16) float s_eb2[16];
    __shared__ __align__(16) float s_ew3[16];
    __shared__ __align__(16) float s_qw1[32];
    __shared__ __align__(16) float s_qb1[16];
    __shared__ __align__(16) float s_qw2[256];
    __shared__ __align__(16) float s_qb2[16];
    __shared__ __align__(16) float s_qw3[16];

    const int tx = threadIdx.x;
    for (int i = tx; i < TLEN; i += 256) {
        s_precp[i] = g_precp[i];
        s_temp[i]  = g_temp[i];
        s_lday[i]  = g_lday[i];
    }
    s_ew2[tx] = g_ew2[tx];
    s_qw2[tx] = g_qw2[tx];
    if (tx < 48) s_ew1[tx] = g_ew1[tx];
    if (tx < 32) s_qw1[tx] = g_qw1[tx];
    if (tx < 16) {
        s_eb1[tx] = g_eb1[tx];
        s_eb2[tx] = g_eb2[tx];
        s_ew3[tx] = g_ew3[tx];
        s_qb1[tx] = g_qb1[tx];
        s_qb2[tx] = g_qb2[tx];
        s_qw3[tx] = g_qw3[tx];
    }
    __syncthreads();

    const int i = blockIdx.x * 256 + tx;
    if (i >= B) return;

    const float Df   = fminf(fmaxf(g_Df[0],   0.01f), 5.0f);
    const float Tmax = fminf(fmaxf(g_Tmax[0], 0.0f),  3.0f);
    const float Tmin = fminf(fmaxf(g_Tmin[0], -3.0f), 0.0f);
    const float eb3  = g_eb3[0];
    const float qb3  = g_qb3[0];

    const float tv = g_t[i];
    const float2 Sv = reinterpret_cast<const float2*>(g_S)[i];
    const float S_snow = Sv.x, S_water = Sv.y;

    int idx = (int)tv;
    idx = max(0, min(idx, TLEN - 2));
    const float fr = tv - (float)idx;
    const float precp = fmaf(fr, s_precp[idx + 1] - s_precp[idx], s_precp[idx]);
    const float temp  = fmaf(fr, s_temp[idx + 1]  - s_temp[idx],  s_temp[idx]);
    const float lday  = fmaf(fr, s_lday[idx + 1]  - s_lday[idx],  s_lday[idx]);

    // ===== ET MLP: inputs [S_snow, S_water, temp] =====
    float h1[16];
    {
        float acc[16];
#pragma unroll
        for (int j = 0; j < 16; ++j) {
            acc[j] = s_eb1[j];
            acc[j] = fmaf(S_snow,  s_ew1[0 * 16 + j], acc[j]);
            acc[j] = fmaf(S_water, s_ew1[1 * 16 + j], acc[j]);
            acc[j] = fmaf(temp,    s_ew1[2 * 16 + j], acc[j]);
        }
#pragma unroll
        for (int j = 0; j < 16; ++j) h1[j] = fast_tanh(acc[j]);
    }
    float h2[16];
    layer16(s_ew2, s_eb2, h1, h2);
    float ET = eb3;
#pragma unroll
    for (int k = 0; k < 16; ++k) ET = fmaf(h2[k], s_ew3[k], ET);

    // ===== Q MLP: inputs [S_water, precp] =====
    float g1[16];
    {
        float acc[16];
#pragma unroll
        for (int j = 0; j < 16; ++j) {
            acc[j] = s_qb1[j];
            acc[j] = fmaf(S_water, s_qw1[0 * 16 + j], acc[j]);
            acc[j] = fmaf(precp,   s_qw1[1 * 16 + j], acc[j]);
        }
#pragma unroll
        for (int j = 0; j < 16; ++j) g1[j] = fast_tanh(acc[j]);
    }
    float g2[16];
    layer16(s_qw2, s_qb2, g1, g2);
    float Q = qb3;
#pragma unroll
    for (int k = 0; k < 16; ++k) Q = fmaf(g2[k], s_qw3[k], Q);

    // ===== bucket dynamics =====
    const float sw_step = step_fn(S_water);
    const float melt = step_fn(temp - Tmax) * step_fn(S_snow)
                     * fminf(S_snow, Df * (temp - Tmax));
    const float dS1 = step_fn(Tmin - temp) * precp - melt;
    const float dS2 = step_fn(temp - Tmin) * precp + melt
                    - sw_step * lday * __expf(ET)
                    - sw_step * __expf(Q);

    reinterpret_cast<float2*>(g_out)[i] = make_float2(dS1, dS2);
}

extern "C" void kernel_launch(void* const* d_in, const int* in_sizes, int n_in,
                              void* d_out, int out_size, void* d_ws, size_t ws_size,
                              hipStream_t stream)
{
    const int B = in_sizes[0];
    const int block = 256;
    const int grid = (B + block - 1) / block;
    hipLaunchKernelGGL(hydro_kernel, dim3(grid), dim3(block), 0, stream,
        (const float*)d_in[0],  // t
        (const float*)d_in[1],  // S
        (const float*)d_in[3],  // precp_series
        (const float*)d_in[4],  // temp_series
        (const float*)d_in[5],  // lday_series
        (const float*)d_in[6],  (const float*)d_in[7],
        (const float*)d_in[8],  (const float*)d_in[9],
        (const float*)d_in[10], (const float*)d_in[11],
        (const float*)d_in[12], (const float*)d_in[13],
        (const float*)d_in[14], (const float*)d_in[15],
        (const float*)d_in[16], (const float*)d_in[17],
        (const float*)d_in[21], // Df
        (const float*)d_in[22], // Tmax
        (const float*)d_in[23], // Tmin
        (float*)d_out, B);
}